// Round 8
// baseline (240.895 us; speedup 1.0000x reference)
//
#include <hip/hip_runtime.h>
#include <hip/hip_bf16.h>

#define B_ 2048
#define N_ 8
#define D_ 1024
#define V_ 4096
#define LN_EPS_ 1e-5f

typedef __bf16 bf16x8 __attribute__((ext_vector_type(8)));
typedef float f32x4 __attribute__((ext_vector_type(4)));

#define GLB(p) ((const __attribute__((address_space(1))) void*)(p))
#define LDSP(p) ((__attribute__((address_space(3))) void*)(p))

static __device__ __forceinline__ unsigned short f2bf(float x) {
    union { float f; unsigned int u; } v;
    v.f = x;
    unsigned int r = v.u + 0x7fffu + ((v.u >> 16) & 1u);
    return (unsigned short)(r >> 16);
}

// ---------------------------------------------------------------------------
// prep: fused  (a) W_pred (N,D,V) f32 -> Wt (N,V,D) bf16   [blocks 2048..10239]
//              (b) gather+cumsum+LN+GELU -> H (N,B,D) bf16 [blocks 0..2047]
// ---------------------------------------------------------------------------
__global__ __launch_bounds__(256) void prep(const float* __restrict__ ie,
                                            const int* __restrict__ feats,
                                            const float* __restrict__ emb,
                                            const float* __restrict__ gamma,
                                            const float* __restrict__ beta,
                                            const float* __restrict__ W,
                                            unsigned short* __restrict__ H,
                                            unsigned short* __restrict__ Wt) {
    const int bid = blockIdx.x;
    const int t = threadIdx.x;

    if (bid >= 2048) {
        __shared__ unsigned short tile[64][65];
        const int w  = bid - 2048;
        const int v0 = (w & 63) * 64;
        const int d0 = ((w >> 6) & 15) * 64;
        const int n  = w >> 10;
        const int tx = t & 15, ty = t >> 4;
#pragma unroll
        for (int i = 0; i < 4; ++i) {
            const int d = ty + i * 16;
            const float4 w4 = *(const float4*)&W[((size_t)n * D_ + d0 + d) * V_ + v0 + tx * 4];
            tile[d][tx * 4 + 0] = f2bf(w4.x);
            tile[d][tx * 4 + 1] = f2bf(w4.y);
            tile[d][tx * 4 + 2] = f2bf(w4.z);
            tile[d][tx * 4 + 3] = f2bf(w4.w);
        }
        __syncthreads();
#pragma unroll
        for (int i = 0; i < 4; ++i) {
            const int v = ty + i * 16;
            ushort4 pk;
            pk.x = tile[tx * 4 + 0][v];
            pk.y = tile[tx * 4 + 1][v];
            pk.z = tile[tx * 4 + 2][v];
            pk.w = tile[tx * 4 + 3][v];
            *reinterpret_cast<ushort4*>(&Wt[((size_t)n * V_ + v0 + v) * D_ + d0 + tx * 4]) = pk;
        }
    } else {
        __shared__ float redS[4], redQ[4];
        const int b = bid;
        const int d0 = t * 4;
        const int lane = t & 63, wid = t >> 6;

        float4 s  = *(const float4*)&ie[(size_t)b * D_ + d0];
        const float4 g4 = *(const float4*)&gamma[d0];
        const float4 be4 = *(const float4*)&beta[d0];

        int fc[N_];
#pragma unroll
        for (int n = 0; n < N_; ++n) fc[n] = feats[b * N_ + n];

#pragma unroll
        for (int n = 0; n < N_; ++n) {
            float ls = s.x + s.y + s.z + s.w;
            float lq = s.x * s.x + s.y * s.y + s.z * s.z + s.w * s.w;
#pragma unroll
            for (int off = 32; off > 0; off >>= 1) {
                ls += __shfl_down(ls, off, 64);
                lq += __shfl_down(lq, off, 64);
            }
            if (lane == 0) { redS[wid] = ls; redQ[wid] = lq; }
            __syncthreads();
            const float tot  = redS[0] + redS[1] + redS[2] + redS[3];
            const float totq = redQ[0] + redQ[1] + redQ[2] + redQ[3];
            __syncthreads();

            const float mu   = tot * (1.0f / D_);
            const float var  = totq * (1.0f / D_) - mu * mu;
            const float rstd = rsqrtf(var + LN_EPS_);

            float h0 = (s.x - mu) * rstd * g4.x + be4.x;
            float h1 = (s.y - mu) * rstd * g4.y + be4.y;
            float h2 = (s.z - mu) * rstd * g4.z + be4.z;
            float h3 = (s.w - mu) * rstd * g4.w + be4.w;
            h0 = 0.5f * h0 * (1.0f + erff(h0 * 0.70710678f));
            h1 = 0.5f * h1 * (1.0f + erff(h1 * 0.70710678f));
            h2 = 0.5f * h2 * (1.0f + erff(h2 * 0.70710678f));
            h3 = 0.5f * h3 * (1.0f + erff(h3 * 0.70710678f));

            ushort4 pk;
            pk.x = f2bf(h0); pk.y = f2bf(h1); pk.z = f2bf(h2); pk.w = f2bf(h3);
            *reinterpret_cast<ushort4*>(&H[((size_t)n * B_ + b) * D_ + d0]) = pk;

            const float4 e = *(const float4*)&emb[((size_t)n * V_ + fc[n]) * (size_t)D_ + d0];
            s.x += e.x; s.y += e.y; s.z += e.z; s.w += e.w;
        }
    }
}

// ---------------------------------------------------------------------------
// gemm2: 256x256 tile, BK=32, 8 waves (2x4, wave-tile 128x64).
// m201 cadence: [ds_reads of tile t][stage t+2][ONE vmcnt(4)][barrier]
// [MFMA cluster 1][reads A4-7][MFMA cluster 2][barrier].
// Reads-at-top are safe: tile t's data confirmed by t-1's vmcnt(4)+barrier
// (2-tile-deep prefetch, 4 LDS buffers x 32KB = 128KB).
// Swizzle (2-way-free for 64B rows): phys 16B slot = logical ^ ((row>>1)&3);
// inverse pre-applied on the global source. Quad map lanes0-7 = {0,4,1,5,2,6,3,7}.
// ---------------------------------------------------------------------------
#define MF(a, b, c) __builtin_amdgcn_mfma_f32_16x16x32_bf16((a), (b), (c), 0, 0, 0)

#define STAGE2(KS, bb) { \
    __builtin_amdgcn_global_load_lds(GLB(Ab + (KS) + (size_t)(srow      ) * D_ + gsl), LDSP(lds + (bb) +         t * 16), 16, 0, 0); \
    __builtin_amdgcn_global_load_lds(GLB(Ab + (KS) + (size_t)(srow + 128) * D_ + gsl), LDSP(lds + (bb) +  8192 + t * 16), 16, 0, 0); \
    __builtin_amdgcn_global_load_lds(GLB(Bb + (KS) + (size_t)(srow      ) * D_ + gsl), LDSP(lds + (bb) + 16384 + t * 16), 16, 0, 0); \
    __builtin_amdgcn_global_load_lds(GLB(Bb + (KS) + (size_t)(srow + 128) * D_ + gsl), LDSP(lds + (bb) + 24576 + t * 16), 16, 0, 0); \
}

#define RD_A2(i, bb) (*(const bf16x8*)(lds + (bb) + ((i) * 32 + wr * 16 + lrow) * 64 + swk))
#define RD_B2(j, bb) (*(const bf16x8*)(lds + (bb) + 16384 + (wc * 64 + (j) * 16 + lrow) * 64 + swk))

#define TILE2(bc, bn, KS, VM, DOSTG) { \
    bf16x8 Bf[4], Af[4]; \
    _Pragma("unroll") for (int j = 0; j < 4; ++j) Bf[j] = RD_B2(j, bc); \
    _Pragma("unroll") for (int i = 0; i < 4; ++i) Af[i] = RD_A2(i, bc); \
    if (DOSTG) { STAGE2(KS, bn); } \
    asm volatile("s_waitcnt vmcnt(" #VM ")" ::: "memory"); \
    __builtin_amdgcn_s_barrier(); \
    __builtin_amdgcn_s_setprio(1); \
    _Pragma("unroll") for (int i = 0; i < 4; ++i) \
        _Pragma("unroll") for (int j = 0; j < 4; ++j) \
            acc[i][j] = MF(Af[i], Bf[j], acc[i][j]); \
    __builtin_amdgcn_s_setprio(0); \
    _Pragma("unroll") for (int i = 0; i < 4; ++i) Af[i] = RD_A2((i) + 4, bc); \
    __builtin_amdgcn_s_setprio(1); \
    _Pragma("unroll") for (int i = 0; i < 4; ++i) \
        _Pragma("unroll") for (int j = 0; j < 4; ++j) \
            acc[i + 4][j] = MF(Af[i], Bf[j], acc[i + 4][j]); \
    __builtin_amdgcn_s_setprio(0); \
    __builtin_amdgcn_s_barrier(); \
}

__global__ __launch_bounds__(512, 2) void gemm2(const unsigned short* __restrict__ H,
                                                const unsigned short* __restrict__ Wt,
                                                const float* __restrict__ bp,
                                                float* __restrict__ out) {
    extern __shared__ char lds[];
    const int bid = blockIdx.x;
    // XCD chunking: XCD k (= bid&7) owns logical range [128k,128k+128) = one n
    const int logical = (bid & 7) * 128 + (bid >> 3);
    const int n  = logical >> 7;
    const int mt = (logical >> 4) & 7;
    const int vt = logical & 15;

    const int t = threadIdx.x;
    const int wid = t >> 6, lane = t & 63;
    const int wr = wid >> 2, wc = wid & 3;

    const unsigned short* Ab = H  + ((size_t)n * B_ + (size_t)mt * 256) * D_;
    const unsigned short* Bb = Wt + ((size_t)n * V_ + (size_t)vt * 256) * D_;

    const int srow = t >> 2;                              // 0..127
    const int gsl  = ((t & 3) ^ ((t >> 3) & 3)) * 8;      // inverse-swizzled source slot
    const int lrow = lane & 15;
    const int lkq  = lane >> 4;
    const int swk  = (lkq ^ ((lrow >> 1) & 3)) * 16;      // 2-way-free read swizzle
    const int col  = lane & 15;
    const int rg   = (lane >> 4) * 4;

    // bias (drained before pipeline)
    float bias[4];
#pragma unroll
    for (int j = 0; j < 4; ++j)
        bias[j] = bp[(size_t)n * V_ + vt * 256 + wc * 64 + j * 16 + col];
    asm volatile("s_waitcnt vmcnt(0)" ::: "memory");
    __builtin_amdgcn_sched_barrier(0);

    f32x4 acc[8][4] = {};

    // prologue: stage tiles 0,1; confirm tile0 (vmcnt(4) leaves tile1 in flight)
    STAGE2(0, 0);
    STAGE2(32, 32768);
    asm volatile("s_waitcnt vmcnt(4)" ::: "memory");
    __builtin_amdgcn_s_barrier();

#pragma unroll 1
    for (int it = 0; it < 7; ++it) {        // tiles 0..27, staging tiles 2..29
        const int ks = it * 128 + 64;
        TILE2(0,     65536, ks,      4, 1);
        TILE2(32768, 98304, ks + 32, 4, 1);
        TILE2(65536, 0,     ks + 64, 4, 1);
        TILE2(98304, 32768, ks + 96, 4, 1);
    }
    TILE2(0,     65536, 960, 4, 1);   // tile 28 stages tile 30
    TILE2(32768, 98304, 992, 4, 1);   // tile 29 stages tile 31
    TILE2(65536, 0,     0,   0, 0);   // tile 30 (vmcnt(0) confirms tile 31)
    TILE2(98304, 0,     0,   0, 0);   // tile 31

    // epilogue: C/D layout col = lane&15, row = (lane>>4)*4 + reg
    const int gc0 = vt * 256 + wc * 64 + col;
#pragma unroll
    for (int i = 0; i < 8; ++i) {
        const int row = mt * 256 + i * 32 + wr * 16 + rg;
#pragma unroll
        for (int j = 0; j < 4; ++j) {
            const int gcol = gc0 + j * 16;
#pragma unroll
            for (int r = 0; r < 4; ++r)
                out[((size_t)(row + r) * N_ + n) * V_ + gcol] = acc[i][j][r] + bias[j];
        }
    }
}

// ---------------------------------------------------------------------------
extern "C" void kernel_launch(void* const* d_in, const int* in_sizes, int n_in,
                              void* d_out, int out_size, void* d_ws, size_t ws_size,
                              hipStream_t stream) {
    const float* ie  = (const float*)d_in[0];
    const int*   fts = (const int*)d_in[1];
    const float* emb = (const float*)d_in[2];
    const float* W   = (const float*)d_in[3];
    const float* bp  = (const float*)d_in[4];
    const float* gam = (const float*)d_in[5];
    const float* bet = (const float*)d_in[6];
    float* out = (float*)d_out;

    unsigned short* Wt = (unsigned short*)d_ws;                                     // 64 MiB
    unsigned short* H  = (unsigned short*)((char*)d_ws + (size_t)N_ * V_ * D_ * 2); // +32 MiB

    (void)hipFuncSetAttribute(reinterpret_cast<const void*>(gemm2),
                              hipFuncAttributeMaxDynamicSharedMemorySize, 131072);

    prep<<<dim3(2048 + 8192), dim3(256), 0, stream>>>(ie, fts, emb, gam, bet, W, H, Wt);
    gemm2<<<dim3(1024), dim3(512), 131072, stream>>>(H, Wt, bp, out);
}